// Round 6
// baseline (318.431 us; speedup 1.0000x reference)
//
#include <hip/hip_runtime.h>
#include <hip/hip_cooperative_groups.h>
#include <math.h>

namespace cg = cooperative_groups;

#define PI_F 3.14159265358979323846f
#define SEG 128
#define SLEN 16
typedef unsigned short u16;
typedef __attribute__((ext_vector_type(8))) short bf16x8;
typedef __attribute__((ext_vector_type(8))) unsigned short u16x8;
typedef __attribute__((ext_vector_type(4))) float f32x4;

__device__ __forceinline__ float sigmoidf_(float x){ return __fdividef(1.0f, 1.0f+__expf(-x)); }
__device__ __forceinline__ float softplusf_(float x){
    return fmaxf(x, 0.f) + __logf(1.f + __expf(-fabsf(x)));
}
__device__ __forceinline__ float tanhpi_(float x){   // tanh(x)*PI
    float t = __expf(-2.f*fabsf(x));
    float th = __fdividef(1.f - t, 1.f + t);
    return copysignf(th, x)*PI_F;
}
__device__ __forceinline__ void fsincos(float a, float* s, float* c){
    float r = a * 0.15915494309189535f;   // a / 2pi
    r = r - floorf(r);                    // [0,1) revolutions
#if __has_builtin(__builtin_amdgcn_sinf)
    *s = __builtin_amdgcn_sinf(r);
    *c = __builtin_amdgcn_cosf(r);
#else
    float t = r * 6.283185307179586f;
    *s = __sinf(t); *c = __cosf(t);
#endif
}
__device__ __forceinline__ u16 f2bf(float f){
    unsigned u = __float_as_uint(f);
    return (u16)((u + 0x7FFFu + ((u>>16)&1u)) >> 16);
}
__device__ __forceinline__ float b2f(u16 v){
    return __uint_as_float(((unsigned)v)<<16);
}
__device__ __forceinline__ void gl_lds16(const u16* g, u16* l){
    __builtin_amdgcn_global_load_lds((const __attribute__((address_space(1))) void*)g,
                                     (__attribute__((address_space(3))) void*)l, 16, 0, 0);
}

// ---------------------------------------------------------------------------
// x fp32 -> bf16 (16384x1024)
// ---------------------------------------------------------------------------
__global__ __launch_bounds__(256) void k_cvt_x(const float* __restrict__ x, u16* __restrict__ xb){
    size_t i = ((size_t)blockIdx.x*256 + threadIdx.x)*8;
    float4 v0 = *(const float4*)&x[i];
    float4 v1 = *(const float4*)&x[i+4];
    ushort4 a = make_ushort4(f2bf(v0.x),f2bf(v0.y),f2bf(v0.z),f2bf(v0.w));
    ushort4 b = make_ushort4(f2bf(v1.x),f2bf(v1.y),f2bf(v1.z),f2bf(v1.w));
    *(ushort4*)&xb[i]   = a;
    *(ushort4*)&xb[i+4] = b;
}

// ---------------------------------------------------------------------------
// Transpose + convert: W[K][Ns] fp32 (k-major) -> Wt[n][KD] bf16, zero-pad k>=K
// ---------------------------------------------------------------------------
__global__ __launch_bounds__(256) void k_tcvt(const float* __restrict__ W, u16* __restrict__ Wt,
                                              int K, int Ns, int KD){
    __shared__ float s[32][33];
    const int tx = threadIdx.x & 31, ty = threadIdx.x >> 5;
    const int k0 = blockIdx.y*32, n0 = blockIdx.x*32;
    #pragma unroll
    for (int i=0;i<4;i++){
        int k = k0 + ty + i*8;
        s[ty+i*8][tx] = (k < K) ? W[(size_t)k*Ns + n0 + tx] : 0.f;
    }
    __syncthreads();
    #pragma unroll
    for (int i=0;i<4;i++){
        int n = n0 + ty + i*8;
        Wt[(size_t)n*KD + k0 + tx] = f2bf(s[tx][ty+i*8]);
    }
}

// ---------------------------------------------------------------------------
// GEMM1 (MFMA): C1[16384 x 896] bf16 = Xb @ Wt^T + bias, XCD swizzle
// ---------------------------------------------------------------------------
__global__ __launch_bounds__(256) void k_mm1(
    const u16* __restrict__ A,
    const u16* __restrict__ Bt,
    const float* __restrict__ bp, const float* __restrict__ bph,
    u16* __restrict__ C)
{
    const int bid = blockIdx.x;
    const int swz = (bid & 7)*112 + (bid >> 3);   // XCD j owns [j*112,(j+1)*112)
    const int by = swz / 7, bx = swz - by*7;

    __shared__ u16 As[128*32];
    __shared__ u16 Bs[128*32];
    const int tid = threadIdx.x;
    const int w = tid>>6, lane = tid&63;
    const int wm = w>>1, wn = w&1;
    const int r0 = by*128, c0 = bx*128;

    const u16* ga[2]; const u16* gb[2]; u16 *la[2], *lb[2];
    #pragma unroll
    for (int i=0;i<2;i++){
        ga[i] = A  + (size_t)(r0 + w*32 + i*16 + (lane>>2))*1024 + (lane&3)*8;
        gb[i] = Bt + (size_t)(c0 + w*32 + i*16 + (lane>>2))*1024 + (lane&3)*8;
        la[i] = As + w*1024 + i*512;
        lb[i] = Bs + w*1024 + i*512;
    }
    const int lr = lane&15, lk = lane>>4;
    const int ao = (wm*64 + lr)*32 + lk*8;
    const int bo = (wn*64 + lr)*32 + lk*8;

    f32x4 acc[4][4] = {};
    for (int k0=0; k0<1024; k0+=32){
        gl_lds16(ga[0]+k0, la[0]); gl_lds16(ga[1]+k0, la[1]);
        gl_lds16(gb[0]+k0, lb[0]); gl_lds16(gb[1]+k0, lb[1]);
        __syncthreads();
        bf16x8 af[4], bfr[4];
        #pragma unroll
        for (int m=0;m<4;m++) af[m]  = *(const bf16x8*)&As[ao + m*512];
        #pragma unroll
        for (int n=0;n<4;n++) bfr[n] = *(const bf16x8*)&Bs[bo + n*512];
        #pragma unroll
        for (int m=0;m<4;m++)
            #pragma unroll
            for (int n=0;n<4;n++)
                acc[m][n] = __builtin_amdgcn_mfma_f32_16x16x32_bf16(af[m], bfr[n], acc[m][n], 0,0,0);
        __syncthreads();
    }
    #pragma unroll
    for (int n=0;n<4;n++){
        int col = c0 + wn*64 + n*16 + lr;
        float bl = (col < 768) ? bp[col] : bph[col-768];
        #pragma unroll
        for (int m=0;m<4;m++){
            int row = r0 + wm*64 + m*16 + lk*4;
            #pragma unroll
            for (int r=0;r<4;r++)
                C[(size_t)(row+r)*896 + col] = f2bf(acc[m][n][r] + bl);
        }
    }
}

// ---------------------------------------------------------------------------
// GEMM2 (MFMA): O[16384x1024] = bf16(X) + rs*( F @ Wrt^T ), XCD swizzle
// Residual read from Xb (bf16) to halve the X stream.
// ---------------------------------------------------------------------------
__global__ __launch_bounds__(256) void k_mm2(
    const u16* __restrict__ A,
    const u16* __restrict__ Bt,
    const u16* __restrict__ Xb,
    const float* __restrict__ rs_p,
    float* __restrict__ O)
{
    const int bid = blockIdx.x;
    const int swz = (bid & 7)*128 + (bid >> 3);
    const int by = swz >> 3, bx = swz & 7;

    __shared__ u16 As[128*32];
    __shared__ u16 Bs[128*32];
    const int tid = threadIdx.x;
    const int w = tid>>6, lane = tid&63;
    const int wm = w>>1, wn = w&1;
    const int r0 = by*128, c0 = bx*128;

    const u16* ga[2]; const u16* gb[2]; u16 *la[2], *lb[2];
    #pragma unroll
    for (int i=0;i<2;i++){
        ga[i] = A  + (size_t)(r0 + w*32 + i*16 + (lane>>2))*512 + (lane&3)*8;
        gb[i] = Bt + (size_t)(c0 + w*32 + i*16 + (lane>>2))*512 + (lane&3)*8;
        la[i] = As + w*1024 + i*512;
        lb[i] = Bs + w*1024 + i*512;
    }
    const int lr = lane&15, lk = lane>>4;
    const int ao = (wm*64 + lr)*32 + lk*8;
    const int bo = (wn*64 + lr)*32 + lk*8;

    f32x4 acc[4][4] = {};
    for (int k0=0; k0<512; k0+=32){
        gl_lds16(ga[0]+k0, la[0]); gl_lds16(ga[1]+k0, la[1]);
        gl_lds16(gb[0]+k0, lb[0]); gl_lds16(gb[1]+k0, lb[1]);
        __syncthreads();
        bf16x8 af[4], bfr[4];
        #pragma unroll
        for (int m=0;m<4;m++) af[m]  = *(const bf16x8*)&As[ao + m*512];
        #pragma unroll
        for (int n=0;n<4;n++) bfr[n] = *(const bf16x8*)&Bs[bo + n*512];
        #pragma unroll
        for (int m=0;m<4;m++)
            #pragma unroll
            for (int n=0;n<4;n++)
                acc[m][n] = __builtin_amdgcn_mfma_f32_16x16x32_bf16(af[m], bfr[n], acc[m][n], 0,0,0);
        __syncthreads();
    }
    const float rs = rs_p[0];
    #pragma unroll
    for (int n=0;n<4;n++){
        int col = c0 + wn*64 + n*16 + lr;
        #pragma unroll
        for (int m=0;m<4;m++){
            int row = r0 + wm*64 + m*16 + lk*4;
            #pragma unroll
            for (int r=0;r<4;r++){
                size_t idx = (size_t)(row+r)*1024 + col;
                O[idx] = b2f(Xb[idx]) + rs*acc[m][n][r];
            }
        }
    }
}

// ---------------------------------------------------------------------------
// Fused scan (cooperative): per block (seg,b) stage 16 C1 rows in LDS once.
// Phase 1: segment aggregates; grid.sync; Phase 2: serial cross-segment scan
// (blocks 0-7); grid.sync; Phase 3: replay + post-scan + feats -> F bf16.
// Math identical to R5's k_s1/k_s2/k_s3.
// ---------------------------------------------------------------------------
__global__ __launch_bounds__(128) void k_scan_fused(
    const u16* __restrict__ C1,
    const float* __restrict__ omega_base,
    const float* __restrict__ lam_p,
    float* __restrict__ Ag, float* __restrict__ Br, float* __restrict__ Bi,
    float* __restrict__ Pr, float* __restrict__ Pi,
    u16* __restrict__ F)
{
    const int k = threadIdx.x;
    const int seg = blockIdx.x, b = blockIdx.y;
    const float ob = omega_base[k];
    const float lam = lam_p[0];

    __shared__ u16 sC[16][896];            // 28672 B
    __shared__ float sre[2][129], sim[2][129];

    // stage 16 rows x 896 cols = 1792 x u16x8, fully coalesced
    {
        const u16* src = C1 + (size_t)(b*2048 + seg*SLEN)*896;
        #pragma unroll
        for (int c=0; c<14; ++c){
            int chunk = c*128 + k;          // 0..1791
            int r = chunk / 112;
            int off = (chunk - r*112)*8;
            *(u16x8*)&sC[r][off] = *(const u16x8*)&src[(size_t)r*896 + off];
        }
    }
    __syncthreads();

    // ---- phase 1: per-segment aggregate ----
    const int n0 = seg*SLEN;
    float aag = 1.f, br = 0.f, bi = 0.f;
    #pragma unroll 4
    for (int s=0; s<SLEN; s++){
        float Ar = b2f(sC[s][k]);
        float Om = b2f(sC[s][128+k]);
        float Ph = b2f(sC[s][256+k]);
        float Ga = b2f(sC[s][384+k]);
        float alpha = sigmoidf_(Ga);
        float A = fminf(softplusf_(Ar), 3.0f);
        float omega = fminf(fmaxf(sigmoidf_(Om)*PI_F + ob, 1e-4f), PI_F-1e-4f);
        float phi = tanhpi_(Ph);
        float pos = __logf(1.f + (float)(n0+s));
        float sa, ca; fsincos(fmaf(omega, pos, phi), &sa, &ca);
        float drive = (1.f-alpha)*A;
        aag *= alpha;
        br = fmaf(alpha, br, drive*ca);
        bi = fmaf(alpha, bi, drive*sa);
    }
    const size_t o = (size_t)(b*SEG + seg)*128 + k;
    Ag[o] = aag; Br[o] = br; Bi[o] = bi;

    cg::this_grid().sync();

    // ---- phase 2: serial scan over segment aggregates (1024 channels) ----
    const int fb = b*gridDim.x + seg;
    if (fb < 8){
        const int gid = fb*128 + k;         // 0..1023
        const int bb = gid >> 7, kk = gid & 127;
        float pr = 0.f, pi = 0.f;
        #pragma unroll 8
        for (int sg=0; sg<SEG; sg++){
            const size_t oo = (size_t)(bb*SEG + sg)*128 + kk;
            float a = Ag[oo], r = Br[oo], i = Bi[oo];
            Pr[oo] = pr; Pi[oo] = pi;
            pr = fmaf(a, pr, r);
            pi = fmaf(a, pi, i);
        }
    }

    cg::this_grid().sync();

    // ---- phase 3: replay + post-scan elementwise + feats ----
    float rr = Pr[o], ri = Pi[o];
    #pragma unroll 2
    for (int s=0; s<SLEN; s++){
        const int n = n0 + s;
        float Ar = b2f(sC[s][k]);
        float Om = b2f(sC[s][128+k]);
        float Ph = b2f(sC[s][256+k]);
        float Ga = b2f(sC[s][384+k]);
        float Go = b2f(sC[s][512+k]);
        float Be = b2f(sC[s][640+k]);
        float pq = b2f(sC[s][768+k]);
        float alpha = sigmoidf_(Ga);
        float A = fminf(softplusf_(Ar), 3.0f);
        float omega = fminf(fmaxf(sigmoidf_(Om)*PI_F + ob, 1e-4f), PI_F-1e-4f);
        float phi = tanhpi_(Ph);
        float pos = __logf(1.f + (float)n);
        float sa, ca; fsincos(fmaf(omega, pos, phi), &sa, &ca);
        float drive = (1.f-alpha)*A;
        rr = fmaf(alpha, rr, drive*ca);
        ri = fmaf(alpha, ri, drive*sa);
        float readout = rr*ca + ri*sa;
        float beta = sigmoidf_(Be);
        float r2r = rr - beta*readout*ca;
        float r2i = ri - beta*readout*sa;
        float m2 = r2r*r2r + r2i*r2i + 1e-8f;
        float inv = fminf(rsqrtf(m2), 1.0f);       // 1/max(sqrt(m2),1)
        r2r *= inv; r2i *= inv;
        float rho_re =  r2r*ca + r2i*sa;
        float rho_im = -r2r*sa + r2i*ca;
        float rho2 = rho_re*rho_re + rho_im*rho_im + 1e-6f;
        float spq, cpq; fsincos(pq, &spq, &cpq);
        float align = (rho_re*cpq + rho_im*spq)*rsqrtf(rho2);
        float gate = sigmoidf_(lam*align);
        rho_re *= gate; rho_im *= gate;
        float go = sigmoidf_(Go);

        const int buf = s & 1;
        sre[buf][k] = rho_re; sim[buf][k] = rho_im;
        __syncthreads();

        u16* frow = F + (size_t)(b*2048+n)*512;
        frow[k]       = f2bf(go*rho_re);
        frow[128 + k] = f2bf(go*rho_im);
        if (k < 127){
            float nre = sre[buf][k+1], nim = sim[buf][k+1];
            frow[256 + k] = f2bf(rho_re*nre + rho_im*nim);
            frow[383 + k] = f2bf(rho_im*nre - rho_re*nim);
        } else {
            frow[510] = 0; frow[511] = 0;
        }
    }
}

extern "C" void kernel_launch(void* const* d_in, const int* in_sizes, int n_in,
                              void* d_out, int out_size, void* d_ws, size_t ws_size,
                              hipStream_t stream)
{
    const float* x   = (const float*)d_in[0];
    const float* Wp  = (const float*)d_in[1];
    const float* bp  = (const float*)d_in[2];
    const float* ob  = (const float*)d_in[3];
    const float* Wph = (const float*)d_in[4];
    const float* bph = (const float*)d_in[5];
    const float* Wr  = (const float*)d_in[6];
    const float* lam = (const float*)d_in[7];
    const float* rs  = (const float*)d_in[8];
    float* out = (float*)d_out;

    char* ws = (char*)d_ws;
    // layout (bytes), total 95158272 (same footprint as R5):
    //   [0, 29360128)            C1 bf16 16384x896
    //   [29360128, +524288)      Ag   | scan scratch + F now live in the old
    //   [29884416, +524288)      Br   | fp32-C1 upper half so Xb stays alive
    //   [30408704, +524288)      Bi   | through k_mm2.
    //   [30932992, +524288)      Pr
    //   [31457280, +524288)      Pi
    //   [31981568, +16777216)    F bf16 16384x512
    //   [58720256, +33554432)    Xb bf16 16384x1024 (live: mm1 A + mm2 residual)
    //   [92274688, +1835008)     Wt bf16 896x1024
    //   [94109696, +1048576)     Wrt bf16 1024x512
    u16*   C1  = (u16*)  (ws + 0);
    float* Ag  = (float*)(ws + 29360128);
    float* Brr = (float*)(ws + 29884416);
    float* Bii = (float*)(ws + 30408704);
    float* Pr  = (float*)(ws + 30932992);
    float* Pi  = (float*)(ws + 31457280);
    u16*   F   = (u16*)  (ws + 31981568);
    u16*   Xb  = (u16*)  (ws + 58720256);
    u16*   Wt  = (u16*)  (ws + 92274688);
    u16*   Wrt = (u16*)  (ws + 94109696);

    dim3 blk(256);
    hipLaunchKernelGGL(k_cvt_x, dim3(8192),   blk, 0, stream, x, Xb);
    hipLaunchKernelGGL(k_tcvt,  dim3(24,32),  blk, 0, stream, Wp,  Wt,            1024, 768,  1024);
    hipLaunchKernelGGL(k_tcvt,  dim3(4,32),   blk, 0, stream, Wph, Wt + 768*1024, 1024, 128,  1024);
    hipLaunchKernelGGL(k_tcvt,  dim3(32,16),  blk, 0, stream, Wr,  Wrt,           510,  1024, 512);
    hipLaunchKernelGGL(k_mm1,   dim3(896),    blk, 0, stream, Xb, Wt, bp, bph, C1);

    const u16* C1c = C1;
    void* args[] = { (void*)&C1c, (void*)&ob, (void*)&lam,
                     (void*)&Ag, (void*)&Brr, (void*)&Bii,
                     (void*)&Pr, (void*)&Pi, (void*)&F };
    hipLaunchCooperativeKernel((const void*)k_scan_fused, dim3(SEG,8), dim3(128),
                               args, 0, stream);

    hipLaunchKernelGGL(k_mm2,   dim3(1024),   blk, 0, stream, F, Wrt, Xb, rs, out);
}

// Round 7
// 148.071 us; speedup vs baseline: 2.1505x; 2.1505x over previous
//
#include <hip/hip_runtime.h>
#include <math.h>

#define PI_F 3.14159265358979323846f
#define SEG 128
#define SLEN 16
typedef unsigned short u16;
typedef __attribute__((ext_vector_type(8))) short bf16x8;
typedef __attribute__((ext_vector_type(4))) float f32x4;

__device__ __forceinline__ float sigmoidf_(float x){ return __fdividef(1.0f, 1.0f+__expf(-x)); }
__device__ __forceinline__ float softplusf_(float x){
    return fmaxf(x, 0.f) + __logf(1.f + __expf(-fabsf(x)));
}
__device__ __forceinline__ float tanhpi_(float x){   // tanh(x)*PI
    float t = __expf(-2.f*fabsf(x));
    float th = __fdividef(1.f - t, 1.f + t);
    return copysignf(th, x)*PI_F;
}
__device__ __forceinline__ void fsincos(float a, float* s, float* c){
    float r = a * 0.15915494309189535f;   // a / 2pi
    r = r - floorf(r);                    // [0,1) revolutions
#if __has_builtin(__builtin_amdgcn_sinf)
    *s = __builtin_amdgcn_sinf(r);
    *c = __builtin_amdgcn_cosf(r);
#else
    float t = r * 6.283185307179586f;
    *s = __sinf(t); *c = __cosf(t);
#endif
}
__device__ __forceinline__ u16 f2bf(float f){
    unsigned u = __float_as_uint(f);
    return (u16)((u + 0x7FFFu + ((u>>16)&1u)) >> 16);
}
__device__ __forceinline__ float b2f(u16 v){
    return __uint_as_float(((unsigned)v)<<16);
}
__device__ __forceinline__ void gl_lds16(const u16* g, u16* l){
    __builtin_amdgcn_global_load_lds((const __attribute__((address_space(1))) void*)g,
                                     (__attribute__((address_space(3))) void*)l, 16, 0, 0);
}

// ---------------------------------------------------------------------------
// x fp32 -> bf16 (16384x1024)
// ---------------------------------------------------------------------------
__global__ __launch_bounds__(256) void k_cvt_x(const float* __restrict__ x, u16* __restrict__ xb){
    size_t i = ((size_t)blockIdx.x*256 + threadIdx.x)*8;
    float4 v0 = *(const float4*)&x[i];
    float4 v1 = *(const float4*)&x[i+4];
    ushort4 a = make_ushort4(f2bf(v0.x),f2bf(v0.y),f2bf(v0.z),f2bf(v0.w));
    ushort4 b = make_ushort4(f2bf(v1.x),f2bf(v1.y),f2bf(v1.z),f2bf(v1.w));
    *(ushort4*)&xb[i]   = a;
    *(ushort4*)&xb[i+4] = b;
}

// ---------------------------------------------------------------------------
// Transpose + convert: W[K][Ns] fp32 (k-major) -> Wt[n][KD] bf16, zero-pad k>=K
// ---------------------------------------------------------------------------
__global__ __launch_bounds__(256) void k_tcvt(const float* __restrict__ W, u16* __restrict__ Wt,
                                              int K, int Ns, int KD){
    __shared__ float s[32][33];
    const int tx = threadIdx.x & 31, ty = threadIdx.x >> 5;
    const int k0 = blockIdx.y*32, n0 = blockIdx.x*32;
    #pragma unroll
    for (int i=0;i<4;i++){
        int k = k0 + ty + i*8;
        s[ty+i*8][tx] = (k < K) ? W[(size_t)k*Ns + n0 + tx] : 0.f;
    }
    __syncthreads();
    #pragma unroll
    for (int i=0;i<4;i++){
        int n = n0 + ty + i*8;
        Wt[(size_t)n*KD + k0 + tx] = f2bf(s[tx][ty+i*8]);
    }
}

// ---------------------------------------------------------------------------
// GEMM1 (MFMA): C1[16384 x 896] bf16 = Xb @ Wt^T + bias, XCD swizzle
// ---------------------------------------------------------------------------
__global__ __launch_bounds__(256) void k_mm1(
    const u16* __restrict__ A,
    const u16* __restrict__ Bt,
    const float* __restrict__ bp, const float* __restrict__ bph,
    u16* __restrict__ C)
{
    const int bid = blockIdx.x;
    const int swz = (bid & 7)*112 + (bid >> 3);   // XCD j owns [j*112,(j+1)*112)
    const int by = swz / 7, bx = swz - by*7;

    __shared__ u16 As[128*32];
    __shared__ u16 Bs[128*32];
    const int tid = threadIdx.x;
    const int w = tid>>6, lane = tid&63;
    const int wm = w>>1, wn = w&1;
    const int r0 = by*128, c0 = bx*128;

    const u16* ga[2]; const u16* gb[2]; u16 *la[2], *lb[2];
    #pragma unroll
    for (int i=0;i<2;i++){
        ga[i] = A  + (size_t)(r0 + w*32 + i*16 + (lane>>2))*1024 + (lane&3)*8;
        gb[i] = Bt + (size_t)(c0 + w*32 + i*16 + (lane>>2))*1024 + (lane&3)*8;
        la[i] = As + w*1024 + i*512;
        lb[i] = Bs + w*1024 + i*512;
    }
    const int lr = lane&15, lk = lane>>4;
    const int ao = (wm*64 + lr)*32 + lk*8;
    const int bo = (wn*64 + lr)*32 + lk*8;

    f32x4 acc[4][4] = {};
    for (int k0=0; k0<1024; k0+=32){
        gl_lds16(ga[0]+k0, la[0]); gl_lds16(ga[1]+k0, la[1]);
        gl_lds16(gb[0]+k0, lb[0]); gl_lds16(gb[1]+k0, lb[1]);
        __syncthreads();
        bf16x8 af[4], bfr[4];
        #pragma unroll
        for (int m=0;m<4;m++) af[m]  = *(const bf16x8*)&As[ao + m*512];
        #pragma unroll
        for (int n=0;n<4;n++) bfr[n] = *(const bf16x8*)&Bs[bo + n*512];
        #pragma unroll
        for (int m=0;m<4;m++)
            #pragma unroll
            for (int n=0;n<4;n++)
                acc[m][n] = __builtin_amdgcn_mfma_f32_16x16x32_bf16(af[m], bfr[n], acc[m][n], 0,0,0);
        __syncthreads();
    }
    #pragma unroll
    for (int n=0;n<4;n++){
        int col = c0 + wn*64 + n*16 + lr;
        float bl = (col < 768) ? bp[col] : bph[col-768];
        #pragma unroll
        for (int m=0;m<4;m++){
            int row = r0 + wm*64 + m*16 + lk*4;
            #pragma unroll
            for (int r=0;r<4;r++)
                C[(size_t)(row+r)*896 + col] = f2bf(acc[m][n][r] + bl);
        }
    }
}

// ---------------------------------------------------------------------------
// GEMM2 (MFMA): O[16384x1024] = bf16(X) + rs*( F @ Wrt^T ), XCD swizzle
// Residual read from Xb (bf16) to halve the X stream.
// ---------------------------------------------------------------------------
__global__ __launch_bounds__(256) void k_mm2(
    const u16* __restrict__ A,
    const u16* __restrict__ Bt,
    const u16* __restrict__ Xb,
    const float* __restrict__ rs_p,
    float* __restrict__ O)
{
    const int bid = blockIdx.x;
    const int swz = (bid & 7)*128 + (bid >> 3);
    const int by = swz >> 3, bx = swz & 7;

    __shared__ u16 As[128*32];
    __shared__ u16 Bs[128*32];
    const int tid = threadIdx.x;
    const int w = tid>>6, lane = tid&63;
    const int wm = w>>1, wn = w&1;
    const int r0 = by*128, c0 = bx*128;

    const u16* ga[2]; const u16* gb[2]; u16 *la[2], *lb[2];
    #pragma unroll
    for (int i=0;i<2;i++){
        ga[i] = A  + (size_t)(r0 + w*32 + i*16 + (lane>>2))*512 + (lane&3)*8;
        gb[i] = Bt + (size_t)(c0 + w*32 + i*16 + (lane>>2))*512 + (lane&3)*8;
        la[i] = As + w*1024 + i*512;
        lb[i] = Bs + w*1024 + i*512;
    }
    const int lr = lane&15, lk = lane>>4;
    const int ao = (wm*64 + lr)*32 + lk*8;
    const int bo = (wn*64 + lr)*32 + lk*8;

    f32x4 acc[4][4] = {};
    for (int k0=0; k0<512; k0+=32){
        gl_lds16(ga[0]+k0, la[0]); gl_lds16(ga[1]+k0, la[1]);
        gl_lds16(gb[0]+k0, lb[0]); gl_lds16(gb[1]+k0, lb[1]);
        __syncthreads();
        bf16x8 af[4], bfr[4];
        #pragma unroll
        for (int m=0;m<4;m++) af[m]  = *(const bf16x8*)&As[ao + m*512];
        #pragma unroll
        for (int n=0;n<4;n++) bfr[n] = *(const bf16x8*)&Bs[bo + n*512];
        #pragma unroll
        for (int m=0;m<4;m++)
            #pragma unroll
            for (int n=0;n<4;n++)
                acc[m][n] = __builtin_amdgcn_mfma_f32_16x16x32_bf16(af[m], bfr[n], acc[m][n], 0,0,0);
        __syncthreads();
    }
    const float rs = rs_p[0];
    #pragma unroll
    for (int n=0;n<4;n++){
        int col = c0 + wn*64 + n*16 + lr;
        #pragma unroll
        for (int m=0;m<4;m++){
            int row = r0 + wm*64 + m*16 + lk*4;
            #pragma unroll
            for (int r=0;r<4;r++){
                size_t idx = (size_t)(row+r)*1024 + col;
                O[idx] = b2f(Xb[idx]) + rs*acc[m][n][r];
            }
        }
    }
}

// ---------------------------------------------------------------------------
// S1: per-segment aggregates. grid (SEG, B), block 128 (thread = k). C1 bf16.
// ---------------------------------------------------------------------------
__global__ __launch_bounds__(128) void k_s1(
    const u16* __restrict__ C1,
    const float* __restrict__ omega_base,
    float* __restrict__ Ag, float* __restrict__ Br, float* __restrict__ Bi)
{
    const int k = threadIdx.x;
    const int seg = blockIdx.x, b = blockIdx.y;
    const float ob = omega_base[k];
    const int n0 = seg*SLEN;
    float aag = 1.f, br = 0.f, bi = 0.f;
    #pragma unroll 4
    for (int s=0; s<SLEN; s++){
        const int n = n0 + s;
        const u16* row = C1 + (size_t)(b*2048+n)*896;
        float Ar = b2f(row[k]);
        float Om = b2f(row[128+k]);
        float Ph = b2f(row[256+k]);
        float Ga = b2f(row[384+k]);
        float alpha = sigmoidf_(Ga);
        float A = fminf(softplusf_(Ar), 3.0f);
        float omega = fminf(fmaxf(sigmoidf_(Om)*PI_F + ob, 1e-4f), PI_F-1e-4f);
        float phi = tanhpi_(Ph);
        float pos = __logf(1.f + (float)n);
        float sa, ca; fsincos(fmaf(omega, pos, phi), &sa, &ca);
        float drive = (1.f-alpha)*A;
        aag *= alpha;
        br = fmaf(alpha, br, drive*ca);
        bi = fmaf(alpha, bi, drive*sa);
    }
    const size_t o = (size_t)(b*SEG + seg)*128 + k;
    Ag[o] = aag; Br[o] = br; Bi[o] = bi;
}

// ---------------------------------------------------------------------------
// S2: serial scan over SEG aggregates per (b,k) channel; writes entry prefix.
// ---------------------------------------------------------------------------
__global__ __launch_bounds__(256) void k_s2(
    const float* __restrict__ Ag, const float* __restrict__ Br, const float* __restrict__ Bi,
    float* __restrict__ Pr, float* __restrict__ Pi)
{
    const int gid = blockIdx.x*256 + threadIdx.x;   // 0..1023
    const int b = gid >> 7, k = gid & 127;
    float pr = 0.f, pi = 0.f;
    #pragma unroll 8
    for (int seg=0; seg<SEG; seg++){
        const size_t o = (size_t)(b*SEG + seg)*128 + k;
        float a = Ag[o], r = Br[o], i = Bi[o];
        Pr[o] = pr; Pi[o] = pi;
        pr = fmaf(a, pr, r);
        pi = fmaf(a, pi, i);
    }
}

// ---------------------------------------------------------------------------
// S3: prefix replay + full post-scan elementwise + neighbor-k cross via LDS,
// writes F bf16 [16384 x 512]. C1 bf16.
// ---------------------------------------------------------------------------
__global__ __launch_bounds__(128) void k_s3(
    const u16* __restrict__ C1,
    const float* __restrict__ omega_base,
    const float* __restrict__ lam_p,
    const float* __restrict__ Pr, const float* __restrict__ Pi,
    u16* __restrict__ F)
{
    const int k = threadIdx.x;
    const int seg = blockIdx.x, b = blockIdx.y;
    const float ob = omega_base[k];
    const float lam = lam_p[0];
    __shared__ float sre[2][129], sim[2][129];

    const size_t po = (size_t)(b*SEG + seg)*128 + k;
    float rr = Pr[po], ri = Pi[po];
    const int n0 = seg*SLEN;

    #pragma unroll 2
    for (int s=0; s<SLEN; s++){
        const int n = n0 + s;
        const u16* row = C1 + (size_t)(b*2048+n)*896;
        float Ar = b2f(row[k]);
        float Om = b2f(row[128+k]);
        float Ph = b2f(row[256+k]);
        float Ga = b2f(row[384+k]);
        float Go = b2f(row[512+k]);
        float Be = b2f(row[640+k]);
        float pq = b2f(row[768+k]);
        float alpha = sigmoidf_(Ga);
        float A = fminf(softplusf_(Ar), 3.0f);
        float omega = fminf(fmaxf(sigmoidf_(Om)*PI_F + ob, 1e-4f), PI_F-1e-4f);
        float phi = tanhpi_(Ph);
        float pos = __logf(1.f + (float)n);
        float sa, ca; fsincos(fmaf(omega, pos, phi), &sa, &ca);
        float drive = (1.f-alpha)*A;
        rr = fmaf(alpha, rr, drive*ca);
        ri = fmaf(alpha, ri, drive*sa);
        float readout = rr*ca + ri*sa;
        float beta = sigmoidf_(Be);
        float r2r = rr - beta*readout*ca;
        float r2i = ri - beta*readout*sa;
        float m2 = r2r*r2r + r2i*r2i + 1e-8f;
        float inv = fminf(rsqrtf(m2), 1.0f);       // 1/max(sqrt(m2),1)
        r2r *= inv; r2i *= inv;
        float rho_re =  r2r*ca + r2i*sa;
        float rho_im = -r2r*sa + r2i*ca;
        float rho2 = rho_re*rho_re + rho_im*rho_im + 1e-6f;
        float spq, cpq; fsincos(pq, &spq, &cpq);
        float align = (rho_re*cpq + rho_im*spq)*rsqrtf(rho2);
        float gate = sigmoidf_(lam*align);
        rho_re *= gate; rho_im *= gate;
        float go = sigmoidf_(Go);

        const int buf = s & 1;
        sre[buf][k] = rho_re; sim[buf][k] = rho_im;
        __syncthreads();

        u16* frow = F + (size_t)(b*2048+n)*512;
        frow[k]       = f2bf(go*rho_re);
        frow[128 + k] = f2bf(go*rho_im);
        if (k < 127){
            float nre = sre[buf][k+1], nim = sim[buf][k+1];
            frow[256 + k] = f2bf(rho_re*nre + rho_im*nim);
            frow[383 + k] = f2bf(rho_im*nre - rho_re*nim);
        } else {
            frow[510] = 0; frow[511] = 0;
        }
    }
}

extern "C" void kernel_launch(void* const* d_in, const int* in_sizes, int n_in,
                              void* d_out, int out_size, void* d_ws, size_t ws_size,
                              hipStream_t stream)
{
    const float* x   = (const float*)d_in[0];
    const float* Wp  = (const float*)d_in[1];
    const float* bp  = (const float*)d_in[2];
    const float* ob  = (const float*)d_in[3];
    const float* Wph = (const float*)d_in[4];
    const float* bph = (const float*)d_in[5];
    const float* Wr  = (const float*)d_in[6];
    const float* lam = (const float*)d_in[7];
    const float* rs  = (const float*)d_in[8];
    float* out = (float*)d_out;

    char* ws = (char*)d_ws;
    // layout (bytes), total 95158272:
    //   [0, 29360128)            C1 bf16 16384x896
    //   [29360128, +524288)      Ag   | scan scratch + F live in the old
    //   [29884416, +524288)      Br   | fp32-C1 upper half so Xb stays alive
    //   [30408704, +524288)      Bi   | through k_mm2.
    //   [30932992, +524288)      Pr
    //   [31457280, +524288)      Pi
    //   [31981568, +16777216)    F bf16 16384x512
    //   [58720256, +33554432)    Xb bf16 16384x1024 (live: mm1 A + mm2 residual)
    //   [92274688, +1835008)     Wt bf16 896x1024
    //   [94109696, +1048576)     Wrt bf16 1024x512
    u16*   C1  = (u16*)  (ws + 0);
    float* Ag  = (float*)(ws + 29360128);
    float* Brr = (float*)(ws + 29884416);
    float* Bii = (float*)(ws + 30408704);
    float* Pr  = (float*)(ws + 30932992);
    float* Pi  = (float*)(ws + 31457280);
    u16*   F   = (u16*)  (ws + 31981568);
    u16*   Xb  = (u16*)  (ws + 58720256);
    u16*   Wt  = (u16*)  (ws + 92274688);
    u16*   Wrt = (u16*)  (ws + 94109696);

    dim3 blk(256);
    hipLaunchKernelGGL(k_cvt_x, dim3(8192),   blk, 0, stream, x, Xb);
    hipLaunchKernelGGL(k_tcvt,  dim3(24,32),  blk, 0, stream, Wp,  Wt,            1024, 768,  1024);
    hipLaunchKernelGGL(k_tcvt,  dim3(4,32),   blk, 0, stream, Wph, Wt + 768*1024, 1024, 128,  1024);
    hipLaunchKernelGGL(k_tcvt,  dim3(32,16),  blk, 0, stream, Wr,  Wrt,           510,  1024, 512);
    hipLaunchKernelGGL(k_mm1,   dim3(896),    blk, 0, stream, Xb, Wt, bp, bph, C1);
    hipLaunchKernelGGL(k_s1,    dim3(SEG,8),  dim3(128), 0, stream, C1, ob, Ag, Brr, Bii);
    hipLaunchKernelGGL(k_s2,    dim3(4),      blk, 0, stream, Ag, Brr, Bii, Pr, Pi);
    hipLaunchKernelGGL(k_s3,    dim3(SEG,8),  dim3(128), 0, stream, C1, ob, lam, Pr, Pi, F);
    hipLaunchKernelGGL(k_mm2,   dim3(1024),   blk, 0, stream, F, Wrt, Xb, rs, out);
}

// Round 8
// 143.779 us; speedup vs baseline: 2.2147x; 1.0298x over previous
//
#include <hip/hip_runtime.h>
#include <math.h>

#define PI_F 3.14159265358979323846f
#define SEG 128
#define SLEN 16
typedef unsigned short u16;
typedef __attribute__((ext_vector_type(8))) short bf16x8;
typedef __attribute__((ext_vector_type(4))) float f32x4;

__device__ __forceinline__ float sigmoidf_(float x){ return __fdividef(1.0f, 1.0f+__expf(-x)); }
__device__ __forceinline__ float softplusf_(float x){
    return fmaxf(x, 0.f) + __logf(1.f + __expf(-fabsf(x)));
}
__device__ __forceinline__ float tanhpi_(float x){   // tanh(x)*PI
    float t = __expf(-2.f*fabsf(x));
    float th = __fdividef(1.f - t, 1.f + t);
    return copysignf(th, x)*PI_F;
}
__device__ __forceinline__ void fsincos(float a, float* s, float* c){
    float r = a * 0.15915494309189535f;   // a / 2pi
    r = r - floorf(r);                    // [0,1) revolutions
#if __has_builtin(__builtin_amdgcn_sinf)
    *s = __builtin_amdgcn_sinf(r);
    *c = __builtin_amdgcn_cosf(r);
#else
    float t = r * 6.283185307179586f;
    *s = __sinf(t); *c = __cosf(t);
#endif
}
__device__ __forceinline__ u16 f2bf(float f){
    unsigned u = __float_as_uint(f);
    return (u16)((u + 0x7FFFu + ((u>>16)&1u)) >> 16);
}
__device__ __forceinline__ float b2f(u16 v){
    return __uint_as_float(((unsigned)v)<<16);
}
__device__ __forceinline__ void gl_lds16(const u16* g, u16* l){
    __builtin_amdgcn_global_load_lds((const __attribute__((address_space(1))) void*)g,
                                     (__attribute__((address_space(3))) void*)l, 16, 0, 0);
}

// ---------------------------------------------------------------------------
// x fp32 -> bf16 (16384x1024)
// ---------------------------------------------------------------------------
__global__ __launch_bounds__(256) void k_cvt_x(const float* __restrict__ x, u16* __restrict__ xb){
    size_t i = ((size_t)blockIdx.x*256 + threadIdx.x)*8;
    float4 v0 = *(const float4*)&x[i];
    float4 v1 = *(const float4*)&x[i+4];
    ushort4 a = make_ushort4(f2bf(v0.x),f2bf(v0.y),f2bf(v0.z),f2bf(v0.w));
    ushort4 b = make_ushort4(f2bf(v1.x),f2bf(v1.y),f2bf(v1.z),f2bf(v1.w));
    *(ushort4*)&xb[i]   = a;
    *(ushort4*)&xb[i+4] = b;
}

// ---------------------------------------------------------------------------
// Transpose + convert: W[K][Ns] fp32 (k-major) -> Wt[n][KD] bf16, zero-pad k>=K
// ---------------------------------------------------------------------------
__global__ __launch_bounds__(256) void k_tcvt(const float* __restrict__ W, u16* __restrict__ Wt,
                                              int K, int Ns, int KD){
    __shared__ float s[32][33];
    const int tx = threadIdx.x & 31, ty = threadIdx.x >> 5;
    const int k0 = blockIdx.y*32, n0 = blockIdx.x*32;
    #pragma unroll
    for (int i=0;i<4;i++){
        int k = k0 + ty + i*8;
        s[ty+i*8][tx] = (k < K) ? W[(size_t)k*Ns + n0 + tx] : 0.f;
    }
    __syncthreads();
    #pragma unroll
    for (int i=0;i<4;i++){
        int n = n0 + ty + i*8;
        Wt[(size_t)n*KD + k0 + tx] = f2bf(s[tx][ty+i*8]);
    }
}

// ---------------------------------------------------------------------------
// GEMM1 (MFMA, pipelined): C1[16384 x 896] bf16 = Xb @ Wt^T + bias
// 256x256 tile, BK=32, 512 thr (8 waves 2x4), 3 LDS buffers, counted vmcnt(4),
// 2 MFMA phases/K-tile with setprio. N padded to 1024 (Wt rows 896..1023 = 0,
// pad columns computed but not stored). Grid 64x4 = 256 blocks = 1/CU.
// ---------------------------------------------------------------------------
__global__ __launch_bounds__(512,1) void k_mm1(
    const u16* __restrict__ A,     // Xb [16384][1024]
    const u16* __restrict__ Bt,    // Wt [1024][1024] (rows >=896 zero)
    const float* __restrict__ bp, const float* __restrict__ bph,
    u16* __restrict__ C)           // [16384][896]
{
    __shared__ u16 sm[3*16384];    // 3 bufs x (A 256x32 | B 256x32) = 96 KB
    const int bid = blockIdx.x;
    const int swz = (bid & 7)*32 + (bid >> 3);  // XCD j owns 32 consecutive swz
    const int by = swz >> 2, bx = swz & 3;
    const int r0 = by*256, c0 = bx*256;
    const int tid = threadIdx.x;
    const int w = tid >> 6, lane = tid & 63;
    const int wm = w >> 2, wn = w & 3;          // 2 x 4 wave grid
    const int lr = lane & 15, lk = lane >> 4;

    // staging: chunk = w*2+j covers 16 rows; lane l -> row +(l>>2), col (l&3)*8
    const u16* gA = A  + (size_t)(r0 + w*32 + (lane>>2))*1024 + (lane&3)*8;
    const u16* gB = Bt + (size_t)(c0 + w*32 + (lane>>2))*1024 + (lane&3)*8;
    const int ldsA = w*1024;            // u16 offset; + j*512
    const int ldsB = 8192 + w*1024;

    // fragment read offsets within a buffer (u16): A rows wm*128+m*16+lr
    const int aoff = (wm*128 + lr)*32 + lk*8;        // + m*512
    const int boff = 8192 + (wn*64 + lr)*32 + lk*8;  // + n*512

    f32x4 acc[8][4] = {};

    // prologue: stage K-tile 0 -> buf0, K-tile 1 -> buf1 (8 loads/wave)
    #pragma unroll
    for (int j=0;j<2;j++){
        gl_lds16(gA + j*16*1024,      sm + ldsA + j*512);
        gl_lds16(gB + j*16*1024,      sm + ldsB + j*512);
    }
    #pragma unroll
    for (int j=0;j<2;j++){
        gl_lds16(gA + j*16*1024 + 32, sm + 16384 + ldsA + j*512);
        gl_lds16(gB + j*16*1024 + 32, sm + 16384 + ldsB + j*512);
    }
    asm volatile("s_waitcnt vmcnt(4)" ::: "memory");   // K-tile 0 resident
    __builtin_amdgcn_s_barrier();
    __builtin_amdgcn_sched_barrier(0);

    for (int k=0; k<32; ++k){
        const u16* bufp = sm + (k%3)*16384;
        u16*       bufn = sm + ((k+2)%3)*16384;
        const int  k0n  = (k+2)*32;
        bf16x8 af[4], bfr[4];

        // ---- phase A: quadrant m0..3, stage next A half ----
        #pragma unroll
        for (int m=0;m<4;m++) af[m]  = *(const bf16x8*)&bufp[aoff + m*512];
        #pragma unroll
        for (int n=0;n<4;n++) bfr[n] = *(const bf16x8*)&bufp[boff + n*512];
        if (k < 30){
            gl_lds16(gA + k0n,           bufn + ldsA);
            gl_lds16(gA + 16*1024 + k0n, bufn + ldsA + 512);
        }
        __builtin_amdgcn_s_barrier();
        __builtin_amdgcn_sched_barrier(0);
        asm volatile("s_waitcnt lgkmcnt(0)" ::: "memory");
        __builtin_amdgcn_sched_barrier(0);
        __builtin_amdgcn_s_setprio(1);
        #pragma unroll
        for (int m=0;m<4;m++)
            #pragma unroll
            for (int n=0;n<4;n++)
                acc[m][n] = __builtin_amdgcn_mfma_f32_16x16x32_bf16(af[m], bfr[n], acc[m][n],0,0,0);
        __builtin_amdgcn_s_setprio(0);
        __builtin_amdgcn_s_barrier();
        __builtin_amdgcn_sched_barrier(0);

        // ---- phase B: quadrant m4..7, stage next B half ----
        #pragma unroll
        for (int m=0;m<4;m++) af[m] = *(const bf16x8*)&bufp[aoff + (m+4)*512];
        if (k < 30){
            gl_lds16(gB + k0n,           bufn + ldsB);
            gl_lds16(gB + 16*1024 + k0n, bufn + ldsB + 512);
        }
        __builtin_amdgcn_s_barrier();
        __builtin_amdgcn_sched_barrier(0);
        asm volatile("s_waitcnt lgkmcnt(0)" ::: "memory");
        __builtin_amdgcn_sched_barrier(0);
        __builtin_amdgcn_s_setprio(1);
        #pragma unroll
        for (int m=0;m<4;m++)
            #pragma unroll
            for (int n=0;n<4;n++)
                acc[m+4][n] = __builtin_amdgcn_mfma_f32_16x16x32_bf16(af[m], bfr[n], acc[m+4][n],0,0,0);
        __builtin_amdgcn_s_setprio(0);
        if (k < 30)       asm volatile("s_waitcnt vmcnt(4)" ::: "memory"); // S(k+1) ready, S(k+2) in flight
        else if (k == 30) asm volatile("s_waitcnt vmcnt(0)" ::: "memory"); // drain for last tile
        __builtin_amdgcn_s_barrier();
        __builtin_amdgcn_sched_barrier(0);
    }

    // epilogue: bias + bf16 store; pad columns (>=896) skipped (wave-uniform)
    if (c0 + wn*64 < 896){
        #pragma unroll
        for (int n=0;n<4;n++){
            const int col = c0 + wn*64 + n*16 + lr;
            const float bl = (col < 768) ? bp[col] : bph[col-768];
            #pragma unroll
            for (int m=0;m<8;m++){
                const int row = r0 + wm*128 + m*16 + lk*4;
                #pragma unroll
                for (int r=0;r<4;r++)
                    C[(size_t)(row+r)*896 + col] = f2bf(acc[m][n][r] + bl);
            }
        }
    }
}

// ---------------------------------------------------------------------------
// GEMM2 (MFMA): O[16384x1024] = bf16(X) + rs*( F @ Wrt^T ), XCD swizzle
// ---------------------------------------------------------------------------
__global__ __launch_bounds__(256) void k_mm2(
    const u16* __restrict__ A,
    const u16* __restrict__ Bt,
    const u16* __restrict__ Xb,
    const float* __restrict__ rs_p,
    float* __restrict__ O)
{
    const int bid = blockIdx.x;
    const int swz = (bid & 7)*128 + (bid >> 3);
    const int by = swz >> 3, bx = swz & 7;

    __shared__ u16 As[128*32];
    __shared__ u16 Bs[128*32];
    const int tid = threadIdx.x;
    const int w = tid>>6, lane = tid&63;
    const int wm = w>>1, wn = w&1;
    const int r0 = by*128, c0 = bx*128;

    const u16* ga[2]; const u16* gb[2]; u16 *la[2], *lb[2];
    #pragma unroll
    for (int i=0;i<2;i++){
        ga[i] = A  + (size_t)(r0 + w*32 + i*16 + (lane>>2))*512 + (lane&3)*8;
        gb[i] = Bt + (size_t)(c0 + w*32 + i*16 + (lane>>2))*512 + (lane&3)*8;
        la[i] = As + w*1024 + i*512;
        lb[i] = Bs + w*1024 + i*512;
    }
    const int lr = lane&15, lk = lane>>4;
    const int ao = (wm*64 + lr)*32 + lk*8;
    const int bo = (wn*64 + lr)*32 + lk*8;

    f32x4 acc[4][4] = {};
    for (int k0=0; k0<512; k0+=32){
        gl_lds16(ga[0]+k0, la[0]); gl_lds16(ga[1]+k0, la[1]);
        gl_lds16(gb[0]+k0, lb[0]); gl_lds16(gb[1]+k0, lb[1]);
        __syncthreads();
        bf16x8 af[4], bfr[4];
        #pragma unroll
        for (int m=0;m<4;m++) af[m]  = *(const bf16x8*)&As[ao + m*512];
        #pragma unroll
        for (int n=0;n<4;n++) bfr[n] = *(const bf16x8*)&Bs[bo + n*512];
        #pragma unroll
        for (int m=0;m<4;m++)
            #pragma unroll
            for (int n=0;n<4;n++)
                acc[m][n] = __builtin_amdgcn_mfma_f32_16x16x32_bf16(af[m], bfr[n], acc[m][n], 0,0,0);
        __syncthreads();
    }
    const float rs = rs_p[0];
    #pragma unroll
    for (int n=0;n<4;n++){
        int col = c0 + wn*64 + n*16 + lr;
        #pragma unroll
        for (int m=0;m<4;m++){
            int row = r0 + wm*64 + m*16 + lk*4;
            #pragma unroll
            for (int r=0;r<4;r++){
                size_t idx = (size_t)(row+r)*1024 + col;
                O[idx] = b2f(Xb[idx]) + rs*acc[m][n][r];
            }
        }
    }
}

// ---------------------------------------------------------------------------
// S1: per-segment aggregates. grid (SEG, B), block 128 (thread = k). C1 bf16.
// ---------------------------------------------------------------------------
__global__ __launch_bounds__(128) void k_s1(
    const u16* __restrict__ C1,
    const float* __restrict__ omega_base,
    float* __restrict__ Ag, float* __restrict__ Br, float* __restrict__ Bi)
{
    const int k = threadIdx.x;
    const int seg = blockIdx.x, b = blockIdx.y;
    const float ob = omega_base[k];
    const int n0 = seg*SLEN;
    float aag = 1.f, br = 0.f, bi = 0.f;
    #pragma unroll 4
    for (int s=0; s<SLEN; s++){
        const int n = n0 + s;
        const u16* row = C1 + (size_t)(b*2048+n)*896;
        float Ar = b2f(row[k]);
        float Om = b2f(row[128+k]);
        float Ph = b2f(row[256+k]);
        float Ga = b2f(row[384+k]);
        float alpha = sigmoidf_(Ga);
        float A = fminf(softplusf_(Ar), 3.0f);
        float omega = fminf(fmaxf(sigmoidf_(Om)*PI_F + ob, 1e-4f), PI_F-1e-4f);
        float phi = tanhpi_(Ph);
        float pos = __logf(1.f + (float)n);
        float sa, ca; fsincos(fmaf(omega, pos, phi), &sa, &ca);
        float drive = (1.f-alpha)*A;
        aag *= alpha;
        br = fmaf(alpha, br, drive*ca);
        bi = fmaf(alpha, bi, drive*sa);
    }
    const size_t o = (size_t)(b*SEG + seg)*128 + k;
    Ag[o] = aag; Br[o] = br; Bi[o] = bi;
}

// ---------------------------------------------------------------------------
// S2: serial scan over SEG aggregates per (b,k) channel; writes entry prefix.
// ---------------------------------------------------------------------------
__global__ __launch_bounds__(256) void k_s2(
    const float* __restrict__ Ag, const float* __restrict__ Br, const float* __restrict__ Bi,
    float* __restrict__ Pr, float* __restrict__ Pi)
{
    const int gid = blockIdx.x*256 + threadIdx.x;   // 0..1023
    const int b = gid >> 7, k = gid & 127;
    float pr = 0.f, pi = 0.f;
    #pragma unroll 8
    for (int seg=0; seg<SEG; seg++){
        const size_t o = (size_t)(b*SEG + seg)*128 + k;
        float a = Ag[o], r = Br[o], i = Bi[o];
        Pr[o] = pr; Pi[o] = pi;
        pr = fmaf(a, pr, r);
        pi = fmaf(a, pi, i);
    }
}

// ---------------------------------------------------------------------------
// S3: prefix replay + full post-scan elementwise + neighbor-k cross via LDS,
// writes F bf16 [16384 x 512]. C1 bf16.
// ---------------------------------------------------------------------------
__global__ __launch_bounds__(128) void k_s3(
    const u16* __restrict__ C1,
    const float* __restrict__ omega_base,
    const float* __restrict__ lam_p,
    const float* __restrict__ Pr, const float* __restrict__ Pi,
    u16* __restrict__ F)
{
    const int k = threadIdx.x;
    const int seg = blockIdx.x, b = blockIdx.y;
    const float ob = omega_base[k];
    const float lam = lam_p[0];
    __shared__ float sre[2][129], sim[2][129];

    const size_t po = (size_t)(b*SEG + seg)*128 + k;
    float rr = Pr[po], ri = Pi[po];
    const int n0 = seg*SLEN;

    #pragma unroll 2
    for (int s=0; s<SLEN; s++){
        const int n = n0 + s;
        const u16* row = C1 + (size_t)(b*2048+n)*896;
        float Ar = b2f(row[k]);
        float Om = b2f(row[128+k]);
        float Ph = b2f(row[256+k]);
        float Ga = b2f(row[384+k]);
        float Go = b2f(row[512+k]);
        float Be = b2f(row[640+k]);
        float pq = b2f(row[768+k]);
        float alpha = sigmoidf_(Ga);
        float A = fminf(softplusf_(Ar), 3.0f);
        float omega = fminf(fmaxf(sigmoidf_(Om)*PI_F + ob, 1e-4f), PI_F-1e-4f);
        float phi = tanhpi_(Ph);
        float pos = __logf(1.f + (float)n);
        float sa, ca; fsincos(fmaf(omega, pos, phi), &sa, &ca);
        float drive = (1.f-alpha)*A;
        rr = fmaf(alpha, rr, drive*ca);
        ri = fmaf(alpha, ri, drive*sa);
        float readout = rr*ca + ri*sa;
        float beta = sigmoidf_(Be);
        float r2r = rr - beta*readout*ca;
        float r2i = ri - beta*readout*sa;
        float m2 = r2r*r2r + r2i*r2i + 1e-8f;
        float inv = fminf(rsqrtf(m2), 1.0f);       // 1/max(sqrt(m2),1)
        r2r *= inv; r2i *= inv;
        float rho_re =  r2r*ca + r2i*sa;
        float rho_im = -r2r*sa + r2i*ca;
        float rho2 = rho_re*rho_re + rho_im*rho_im + 1e-6f;
        float spq, cpq; fsincos(pq, &spq, &cpq);
        float align = (rho_re*cpq + rho_im*spq)*rsqrtf(rho2);
        float gate = sigmoidf_(lam*align);
        rho_re *= gate; rho_im *= gate;
        float go = sigmoidf_(Go);

        const int buf = s & 1;
        sre[buf][k] = rho_re; sim[buf][k] = rho_im;
        __syncthreads();

        u16* frow = F + (size_t)(b*2048+n)*512;
        frow[k]       = f2bf(go*rho_re);
        frow[128 + k] = f2bf(go*rho_im);
        if (k < 127){
            float nre = sre[buf][k+1], nim = sim[buf][k+1];
            frow[256 + k] = f2bf(rho_re*nre + rho_im*nim);
            frow[383 + k] = f2bf(rho_im*nre - rho_re*nim);
        } else {
            frow[510] = 0; frow[511] = 0;
        }
    }
}

extern "C" void kernel_launch(void* const* d_in, const int* in_sizes, int n_in,
                              void* d_out, int out_size, void* d_ws, size_t ws_size,
                              hipStream_t stream)
{
    const float* x   = (const float*)d_in[0];
    const float* Wp  = (const float*)d_in[1];
    const float* bp  = (const float*)d_in[2];
    const float* ob  = (const float*)d_in[3];
    const float* Wph = (const float*)d_in[4];
    const float* bph = (const float*)d_in[5];
    const float* Wr  = (const float*)d_in[6];
    const float* lam = (const float*)d_in[7];
    const float* rs  = (const float*)d_in[8];
    float* out = (float*)d_out;

    char* ws = (char*)d_ws;
    // layout (bytes), max 92274688 (shrunk vs R7):
    //   [0, 29360128)            C1 bf16 16384x896
    //   [29360128, +524288)      Ag
    //   [29884416, +524288)      Br
    //   [30408704, +524288)      Bi
    //   [30932992, +524288)      Pr
    //   [31457280, +524288)      Pi
    //   [31981568, +16777216)    F bf16 16384x512
    //   [48758784, +2097152)     Wt bf16 1024x1024 (rows 896..1023 zero)
    //   [50855936, +1048576)     Wrt bf16 1024x512
    //   [58720256, +33554432)    Xb bf16 16384x1024
    u16*   C1  = (u16*)  (ws + 0);
    float* Ag  = (float*)(ws + 29360128);
    float* Brr = (float*)(ws + 29884416);
    float* Bii = (float*)(ws + 30408704);
    float* Pr  = (float*)(ws + 30932992);
    float* Pi  = (float*)(ws + 31457280);
    u16*   F   = (u16*)  (ws + 31981568);
    u16*   Wt  = (u16*)  (ws + 48758784);
    u16*   Wrt = (u16*)  (ws + 50855936);
    u16*   Xb  = (u16*)  (ws + 58720256);

    dim3 blk(256);
    hipMemsetAsync(Wt, 0, 2097152, stream);   // zero pad rows 896..1023
    hipLaunchKernelGGL(k_cvt_x, dim3(8192),   blk, 0, stream, x, Xb);
    hipLaunchKernelGGL(k_tcvt,  dim3(24,32),  blk, 0, stream, Wp,  Wt,            1024, 768,  1024);
    hipLaunchKernelGGL(k_tcvt,  dim3(4,32),   blk, 0, stream, Wph, Wt + 768*1024, 1024, 128,  1024);
    hipLaunchKernelGGL(k_tcvt,  dim3(32,16),  blk, 0, stream, Wr,  Wrt,           510,  1024, 512);
    hipLaunchKernelGGL(k_mm1,   dim3(256),    dim3(512), 0, stream, Xb, Wt, bp, bph, C1);
    hipLaunchKernelGGL(k_s1,    dim3(SEG,8),  dim3(128), 0, stream, C1, ob, Ag, Brr, Bii);
    hipLaunchKernelGGL(k_s2,    dim3(4),      blk, 0, stream, Ag, Brr, Bii, Pr, Pi);
    hipLaunchKernelGGL(k_s3,    dim3(SEG,8),  dim3(128), 0, stream, C1, ob, lam, Pr, Pi, F);
    hipLaunchKernelGGL(k_mm2,   dim3(1024),   blk, 0, stream, F, Wrt, Xb, rs, out);
}